// Round 2
// baseline (537.068 us; speedup 1.0000x reference)
//
#include <hip/hip_runtime.h>
#include <hip/hip_bf16.h>

#define LDST 136                 // padded LDS row stride (bf16), 272 B = 16B-aligned
#define ACT_ELEMS (64 * LDST)    // one activation buffer: 64 rows x 136
#define WCHUNK 16384             // weight chunk in global: 128 n x 128 k (bf16, no pad)

typedef __bf16 bf16x8 __attribute__((ext_vector_type(8)));
typedef float  f32x4  __attribute__((ext_vector_type(4)));

// ---------------- prep: fp32 [k][n] -> bf16 [chunk][n][k] via LDS transpose ----------------
// chunks: 0-2 ne_w (K=384), 3 ne1_w, 4 att1_w[:128] (x part), 5 att2_w
__global__ void prep_weights_kernel(const float* __restrict__ ne_w,
                                    const float* __restrict__ ne1_w,
                                    const float* __restrict__ att1_w,
                                    const float* __restrict__ att2_w,
                                    __hip_bfloat16* __restrict__ wout) {
  __shared__ float tile[64][65];
  const int bx = blockIdx.x;
  const int c = bx >> 2, kt = (bx >> 1) & 1, ntile = bx & 1;
  const float* src; int koff;
  if      (c < 3)  { src = ne_w;   koff = c * 128; }
  else if (c == 3) { src = ne1_w;  koff = 0; }
  else if (c == 4) { src = att1_w; koff = 0; }
  else             { src = att2_w; koff = 0; }
  const int tx = threadIdx.x, ty = threadIdx.y;
#pragma unroll
  for (int r = 0; r < 16; ++r) {
    int k = kt * 64 + r * 4 + ty, n = ntile * 64 + tx;
    tile[r * 4 + ty][tx] = src[(koff + k) * 128 + n];   // coalesced over n
  }
  __syncthreads();
#pragma unroll
  for (int r = 0; r < 16; ++r) {
    int n = ntile * 64 + r * 4 + ty, k = kt * 64 + tx;
    wout[(c * 128 + n) * 128 + k] = __float2bfloat16(tile[tx][r * 4 + ty]); // coalesced over k
  }
}

// ---------------- helpers ----------------
__device__ __forceinline__ unsigned short bf_bits(float x) {
  return __builtin_bit_cast(unsigned short, __float2bfloat16(x));
}

// A from LDS rows (stride LDST), B direct from global bf16 [n][128]; wave tile 16(m) x 64(n)
__device__ __forceinline__ void mfma_chunk(const __hip_bfloat16* sIn,
                                           const __hip_bfloat16* __restrict__ gB,
                                           f32x4 acc[4], int m16, int nh, int lane) {
  const int mr = lane & 15;
  const int kq = (lane >> 4) << 3;
  const int arow = (m16 * 16 + mr) * LDST;
#pragma unroll
  for (int ks = 0; ks < 4; ++ks) {
    const int kk = ks * 32 + kq;
    bf16x8 a = *(const bf16x8*)(sIn + arow + kk);
#pragma unroll
    for (int nt = 0; nt < 4; ++nt) {
      const int n = nh * 64 + nt * 16 + mr;
      bf16x8 b = *(const bf16x8*)(gB + n * 128 + kk);
      acc[nt] = __builtin_amdgcn_mfma_f32_16x16x32_bf16(a, b, acc[nt], 0, 0, 0);
    }
  }
}

// bias + optional row-vector add + relu + bf16 store; C/D: col=lane&15, row=(lane>>4)*4+reg
__device__ __forceinline__ void epilogue(f32x4 acc[4], const float* __restrict__ bias,
                                         const float* addvec, __hip_bfloat16* sOut,
                                         int m16, int nh, int lane) {
  const int cb = nh * 64 + (lane & 15);
  const int rb = m16 * 16 + ((lane >> 4) << 2);
#pragma unroll
  for (int nt = 0; nt < 4; ++nt) {
    const int col = cb + nt * 16;
    float bv = bias[col];
    if (addvec) bv += addvec[col];
#pragma unroll
    for (int r = 0; r < 4; ++r) {
      float v = fmaxf(acc[nt][r] + bv, 0.0f);
      sOut[(rb + r) * LDST + col] = __float2bfloat16(v);
    }
  }
}

// ---------------- main fused kernel: 1 block = 1 user, M=64 rows (50 real) ----------------
__global__ __launch_bounds__(512, 4) void graphdec_main(
    const float* __restrict__ u2e, const float* __restrict__ i2e,
    const float* __restrict__ r2e, const float* __restrict__ t2e,
    const float* __restrict__ ne_b, const float* __restrict__ ne1_b,
    const float* __restrict__ att1_w, const float* __restrict__ att1_b,
    const float* __restrict__ att3_w, const float* __restrict__ att3_b,
    const float* __restrict__ att2_b,
    const float* __restrict__ lin_w, const float* __restrict__ lin_b,
    const float* __restrict__ w1_w, const float* __restrict__ w1_b,
    const float* __restrict__ bn1_g, const float* __restrict__ bn1_b,
    const float* __restrict__ bn1_m, const float* __restrict__ bn1_v,
    const float* __restrict__ w2_w, const float* __restrict__ w2_b,
    const float* __restrict__ bn2_g, const float* __restrict__ bn2_b,
    const float* __restrict__ bn2_m, const float* __restrict__ bn2_v,
    const float* __restrict__ w3_w, const float* __restrict__ w3_b,
    const int* __restrict__ user_idx, const int* __restrict__ item_idx,
    const int* __restrict__ rat_idx, const int* __restrict__ time_idx,
    const __hip_bfloat16* __restrict__ wprep, float* __restrict__ out) {
  __shared__ __align__(16) __hip_bfloat16 sA[ACT_ELEMS];  // gather / a1
  __shared__ __align__(16) __hip_bfloat16 sB[ACT_ELEMS];  // gather / x1 / a2
  __shared__ __align__(16) __hip_bfloat16 sX[ACT_ELEMS];  // x (persists to pooling)
  __shared__ float sUf[128];
  __shared__ int   sIdx[3 * 64];
  __shared__ float sAtt3[128];
  __shared__ float sUatt4[4 * 128];
  __shared__ float sUatt[128];
  __shared__ float sLogit[64];
  __shared__ float sAtt[64];
  __shared__ float sPool4[4 * 128];
  __shared__ float sPooled[128];
  __shared__ float sCombP[4 * 128];
  __shared__ float sComb[128];
  __shared__ float sH1p[4 * 32];
  __shared__ float sH1[32];
  __shared__ float sH2[16];

  const int tid  = threadIdx.x;
  const int lane = tid & 63;
  const int wid  = tid >> 6;
  const int m16  = wid & 3;   // 16-row group of M=64
  const int nh   = wid >> 2;  // 64-col half of N=128
  const int b    = blockIdx.x;

  // ---- preload indices, user embedding, att3 ----
  if (tid < 192) {
    int c = tid >> 6, l = tid & 63;
    int v = 0;
    if (l < 50) {
      const int* p = (c == 0) ? item_idx : (c == 1) ? rat_idx : time_idx;
      v = p[b * 50 + l];
    }
    sIdx[tid] = v;
  } else if (tid < 320) {
    sAtt3[tid - 192] = att3_w[tid - 192];
  } else if (tid < 448) {
    sUf[tid - 320] = u2e[user_idx[b] * 128 + (tid - 320)];
  }
  __syncthreads();

  // gather one table chunk into dst (bf16), rows >= 50 zeroed
  auto gather = [&](int c, const float* __restrict__ tab, __hip_bfloat16* dst) {
    const float4* t4 = (const float4*)tab;
#pragma unroll
    for (int i = 0; i < 4; ++i) {
      int g = tid + i * 512;           // 2048 = 64 rows x 32 float4
      int row = g >> 5, q4 = g & 31;
      float4 v = {0.f, 0.f, 0.f, 0.f};
      if (row < 50) v = t4[(long)sIdx[c * 64 + row] * 32 + q4];
      ushort4 pk;
      pk.x = bf_bits(v.x); pk.y = bf_bits(v.y); pk.z = bf_bits(v.z); pk.w = bf_bits(v.w);
      *(ushort4*)(dst + row * LDST + q4 * 4) = pk;
    }
  };

  f32x4 acc[4];
  const f32x4 zf = {0.f, 0.f, 0.f, 0.f};
  auto zacc = [&]() {
#pragma unroll
    for (int j = 0; j < 4; ++j) acc[j] = zf;
  };

  // ===== phase 0: gather item chunk; u@att1_w[128:] partials (fp32) =====
  gather(0, i2e, sA);
  {
    int q = tid >> 7, d = tid & 127;
    float s = 0.f;
    for (int k = q * 32; k < q * 32 + 32; ++k) s += sUf[k] * att1_w[(128 + k) * 128 + d];
    sUatt4[q * 128 + d] = s;
  }
  __syncthreads();

  // ===== ne layer: K=384 over 3 chunks =====
  zacc();
  mfma_chunk(sA, wprep + 0 * WCHUNK, acc, m16, nh, lane);
  gather(1, r2e, sB);
  if (tid < 128) sUatt[tid] = sUatt4[tid] + sUatt4[128 + tid] + sUatt4[256 + tid] + sUatt4[384 + tid];
  __syncthreads();
  mfma_chunk(sB, wprep + 1 * WCHUNK, acc, m16, nh, lane);
  gather(2, t2e, sA);
  __syncthreads();
  mfma_chunk(sA, wprep + 2 * WCHUNK, acc, m16, nh, lane);
  epilogue(acc, ne_b, nullptr, sB, m16, nh, lane);   // x1 -> sB
  __syncthreads();

  // ===== ne1: x = relu(x1 @ ne1_w + b) =====
  zacc();
  mfma_chunk(sB, wprep + 3 * WCHUNK, acc, m16, nh, lane);
  epilogue(acc, ne1_b, nullptr, sX, m16, nh, lane);  // x -> sX
  __syncthreads();

  // ===== att1: a1 = relu(x @ att1_w[:128] + u@att1_w[128:] + b) =====
  zacc();
  mfma_chunk(sX, wprep + 4 * WCHUNK, acc, m16, nh, lane);
  epilogue(acc, att1_b, sUatt, sA, m16, nh, lane);   // a1 -> sA
  __syncthreads();

  // ===== att2: a2 = relu(a1 @ att2_w + b) =====
  zacc();
  mfma_chunk(sA, wprep + 5 * WCHUNK, acc, m16, nh, lane);
  epilogue(acc, att2_b, nullptr, sB, m16, nh, lane); // a2 -> sB
  __syncthreads();

  // ===== logits: a2 @ att3  (8 lanes per row, shuffle-reduce) =====
  {
    int row = tid >> 3, p = tid & 7;
    const __hip_bfloat16* rp = sB + row * LDST + p * 16;
    float s = 0.f;
#pragma unroll
    for (int kk = 0; kk < 16; ++kk) s += __bfloat162float(rp[kk]) * sAtt3[p * 16 + kk];
    s += __shfl_xor(s, 1); s += __shfl_xor(s, 2); s += __shfl_xor(s, 4);
    if (p == 0) sLogit[row] = s + att3_b[0];
  }
  __syncthreads();

  // ===== softmax over 50 (wave 0) =====
  if (wid == 0) {
    float v = (lane < 50) ? sLogit[lane] : -3.4e38f;
    float m = v;
    for (int off = 32; off > 0; off >>= 1) m = fmaxf(m, __shfl_xor(m, off));
    float e = (lane < 50) ? __expf(v - m) : 0.f;
    float s = e;
    for (int off = 32; off > 0; off >>= 1) s += __shfl_xor(s, off);
    sAtt[lane] = e / s;
  }
  __syncthreads();

  // ===== pooled = sum_l att[l] * x[l,:]  (4 partials per d) =====
  {
    int q = tid >> 7, d = tid & 127;
    float s = 0.f;
    for (int l = q; l < 50; l += 4) s += sAtt[l] * __bfloat162float(sX[l * LDST + d]);
    sPool4[q * 128 + d] = s;
  }
  __syncthreads();
  if (tid < 128) sPooled[tid] = sPool4[tid] + sPool4[128 + tid] + sPool4[256 + tid] + sPool4[384 + tid];
  __syncthreads();

  // ===== comb = relu(concat(u, pooled) @ lin_w + lin_b)  (4 partials per d) =====
  {
    int q = tid >> 7, d = tid & 127;
    const float* inb = (q < 2) ? (sUf + q * 64) : (sPooled + (q - 2) * 64);
    const int base = q * 64;
    float s = 0.f;
    for (int j = 0; j < 64; ++j) s += inb[j] * lin_w[(base + j) * 128 + d];
    sCombP[q * 128 + d] = s;
  }
  __syncthreads();
  if (tid < 128)
    sComb[tid] = fmaxf(sCombP[tid] + sCombP[128 + tid] + sCombP[256 + tid] + sCombP[384 + tid]
                       + lin_b[tid], 0.f);
  __syncthreads();

  // ===== head: 128 -> 32 (bn1) -> 16 (bn2) -> 1 =====
  if (tid < 128) {
    int j = tid & 31, q = tid >> 5;
    float s = 0.f;
    for (int k = q * 32; k < q * 32 + 32; ++k) s += sComb[k] * w1_w[k * 32 + j];
    sH1p[q * 32 + j] = s;
  }
  __syncthreads();
  if (tid < 32) {
    float s = sH1p[tid] + sH1p[32 + tid] + sH1p[64 + tid] + sH1p[96 + tid] + w1_b[tid];
    s = (s - bn1_m[tid]) * rsqrtf(bn1_v[tid] + 1e-5f) * bn1_g[tid] + bn1_b[tid];
    sH1[tid] = fmaxf(s, 0.f);
  }
  __syncthreads();
  if (tid < 16) {
    float s = w2_b[tid];
    for (int k = 0; k < 32; ++k) s += sH1[k] * w2_w[k * 16 + tid];
    s = (s - bn2_m[tid]) * rsqrtf(bn2_v[tid] + 1e-5f) * bn2_g[tid] + bn2_b[tid];
    sH2[tid] = fmaxf(s, 0.f);
  }
  __syncthreads();
  if (tid == 0) {
    float s = w3_b[0];
    for (int k = 0; k < 16; ++k) s += sH2[k] * w3_w[k];
    out[b] = s;
  }
}

extern "C" void kernel_launch(void* const* d_in, const int* in_sizes, int n_in,
                              void* d_out, int out_size, void* d_ws, size_t ws_size,
                              hipStream_t stream) {
  const float* u2e    = (const float*)d_in[0];
  const float* i2e    = (const float*)d_in[1];
  const float* r2e    = (const float*)d_in[2];
  const float* t2e    = (const float*)d_in[3];
  const float* ne_w   = (const float*)d_in[4];
  const float* ne_b   = (const float*)d_in[5];
  const float* ne1_w  = (const float*)d_in[6];
  const float* ne1_b  = (const float*)d_in[7];
  const float* att1_w = (const float*)d_in[8];
  const float* att1_b = (const float*)d_in[9];
  const float* att2_w = (const float*)d_in[10];
  const float* att2_b = (const float*)d_in[11];
  const float* att3_w = (const float*)d_in[12];
  const float* att3_b = (const float*)d_in[13];
  const float* lin_w  = (const float*)d_in[14];
  const float* lin_b  = (const float*)d_in[15];
  const float* w1_w   = (const float*)d_in[16];
  const float* w1_b   = (const float*)d_in[17];
  const float* bn1_g  = (const float*)d_in[18];
  const float* bn1_b  = (const float*)d_in[19];
  const float* bn1_m  = (const float*)d_in[20];
  const float* bn1_v  = (const float*)d_in[21];
  const float* w2_w   = (const float*)d_in[22];
  const float* w2_b   = (const float*)d_in[23];
  const float* bn2_g  = (const float*)d_in[24];
  const float* bn2_b  = (const float*)d_in[25];
  const float* bn2_m  = (const float*)d_in[26];
  const float* bn2_v  = (const float*)d_in[27];
  const float* w3_w   = (const float*)d_in[28];
  const float* w3_b   = (const float*)d_in[29];
  const int* user_idx = (const int*)d_in[30];
  const int* item_idx = (const int*)d_in[31];
  const int* rat_idx  = (const int*)d_in[32];
  const int* time_idx = (const int*)d_in[33];
  __hip_bfloat16* wprep = (__hip_bfloat16*)d_ws;
  float* out = (float*)d_out;

  prep_weights_kernel<<<24, dim3(64, 4), 0, stream>>>(ne_w, ne1_w, att1_w, att2_w, wprep);
  graphdec_main<<<4096, 512, 0, stream>>>(
      u2e, i2e, r2e, t2e, ne_b, ne1_b, att1_w, att1_b, att3_w, att3_b, att2_b,
      lin_w, lin_b, w1_w, w1_b, bn1_g, bn1_b, bn1_m, bn1_v, w2_w, w2_b,
      bn2_g, bn2_b, bn2_m, bn2_v, w3_w, w3_b,
      user_idx, item_idx, rat_idx, time_idx, wprep, out);
}

// Round 4
// 300.105 us; speedup vs baseline: 1.7896x; 1.7896x over previous
//
#include <hip/hip_runtime.h>
#include <hip/hip_bf16.h>

typedef __bf16 bf16x8 __attribute__((ext_vector_type(8)));
typedef float  f32x4  __attribute__((ext_vector_type(4)));

// LDS layout (bytes). Activations: 52 rows x 128 bf16, XOR-swizzled 16B k-blocks.
#define W_OFF 0            // weight chunk: 128n x 128k bf16, swizzled   (32768 B)
#define A_OFF 32768        // act buf A (13312 B)
#define B_OFF 46080        // act buf B (13312 B)
#define X_OFF 59392        // act buf X (13312 B)
#define SMALL 72704        // small persistent arrays (~4 KB)
#define SMEM_TOTAL 76736
#define WCHUNK 16384       // bf16 elems per weight chunk in global

// ---------------- prep: fp32 [k][n] -> bf16 [chunk][n][swizzled k] ----------------
// chunks: 0-2 ne_w (K=384), 3 ne1_w, 4 att1_w[:128] (x part), 5 att2_w
__global__ void prep_weights_kernel(const float* __restrict__ ne_w,
                                    const float* __restrict__ ne1_w,
                                    const float* __restrict__ att1_w,
                                    const float* __restrict__ att2_w,
                                    __hip_bfloat16* __restrict__ wout) {
  __shared__ float tile[64][65];
  const int bx = blockIdx.x;
  const int c = bx >> 2, kt = (bx >> 1) & 1, ntile = bx & 1;
  const float* src; int koff;
  if      (c < 3)  { src = ne_w;   koff = c * 128; }
  else if (c == 3) { src = ne1_w;  koff = 0; }
  else if (c == 4) { src = att1_w; koff = 0; }
  else             { src = att2_w; koff = 0; }
  const int tx = threadIdx.x, ty = threadIdx.y;
#pragma unroll
  for (int r = 0; r < 16; ++r) {
    int k = kt * 64 + r * 4 + ty, n = ntile * 64 + tx;
    tile[r * 4 + ty][tx] = src[(koff + k) * 128 + n];   // coalesced over n
  }
  __syncthreads();
#pragma unroll
  for (int r = 0; r < 16; ++r) {
    int n = ntile * 64 + r * 4 + ty, k = kt * 64 + tx;  // chunk-local k in [0,128)
    int off = (c * 128 + n) * 128 + (((k >> 3) ^ (n & 15)) << 3) + (k & 7);
    wout[off] = __float2bfloat16(tile[tx][r * 4 + ty]);
  }
}

// ---------------- helpers ----------------
__device__ __forceinline__ unsigned short bf_bits(float x) {
  return __builtin_bit_cast(unsigned short, __float2bfloat16(x));
}

// A from swizzled act buffer, B from swizzled LDS weight chunk; wave tile 16m x 64n
__device__ __forceinline__ void mfma_chunk(const __hip_bfloat16* sIn,
                                           const __hip_bfloat16* sWl,
                                           f32x4 acc[4], int m16, int nh, int lane) {
  const int mr = lane & 15;
  const int kq = lane >> 4;            // 0..3
  const int arow = (m16 * 16 + mr) * 128;
#pragma unroll
  for (int ks = 0; ks < 4; ++ks) {
    const int swz = (((ks * 4 + kq) ^ mr) << 3);
    bf16x8 a = *(const bf16x8*)(sIn + arow + swz);
#pragma unroll
    for (int nt = 0; nt < 4; ++nt) {
      const int n = nh * 64 + nt * 16 + mr;   // n&15 == mr -> same swz as A
      bf16x8 b = *(const bf16x8*)(sWl + n * 128 + swz);
      acc[nt] = __builtin_amdgcn_mfma_f32_16x16x32_bf16(a, b, acc[nt], 0, 0, 0);
    }
  }
}

// bias + optional row-vector + relu + swizzled bf16 store (rows < 50 only)
__device__ __forceinline__ void epilogue(f32x4 acc[4], const float* __restrict__ bias,
                                         const float* addvec, __hip_bfloat16* sOut,
                                         int m16, int nh, int lane) {
  const int mr = lane & 15;
  const int rb = m16 * 16 + ((lane >> 4) << 2);
#pragma unroll
  for (int nt = 0; nt < 4; ++nt) {
    const int col = nh * 64 + nt * 16 + mr;
    float bv = bias[col];
    if (addvec) bv += addvec[col];
    const int cblk = col >> 3, clo = col & 7;
#pragma unroll
    for (int r = 0; r < 4; ++r) {
      const int row = rb + r;
      if (row < 50) {
        float v = fmaxf(acc[nt][r] + bv, 0.0f);
        sOut[row * 128 + ((cblk ^ (row & 15)) << 3) + clo] = __float2bfloat16(v);
      }
    }
  }
}

// ---------------- main fused kernel: 1 block = 1 user, 2 blocks/CU ----------------
__global__ __launch_bounds__(512, 4) void graphdec_main(
    const float* __restrict__ u2e, const float* __restrict__ i2e,
    const float* __restrict__ r2e, const float* __restrict__ t2e,
    const float* __restrict__ ne_b, const float* __restrict__ ne1_b,
    const float* __restrict__ att1_w, const float* __restrict__ att1_b,
    const float* __restrict__ att3_w, const float* __restrict__ att3_b,
    const float* __restrict__ att2_b,
    const float* __restrict__ lin_w, const float* __restrict__ lin_b,
    const float* __restrict__ w1_w, const float* __restrict__ w1_b,
    const float* __restrict__ bn1_g, const float* __restrict__ bn1_b,
    const float* __restrict__ bn1_m, const float* __restrict__ bn1_v,
    const float* __restrict__ w2_w, const float* __restrict__ w2_b,
    const float* __restrict__ bn2_g, const float* __restrict__ bn2_b,
    const float* __restrict__ bn2_m, const float* __restrict__ bn2_v,
    const float* __restrict__ w3_w, const float* __restrict__ w3_b,
    const int* __restrict__ user_idx, const int* __restrict__ item_idx,
    const int* __restrict__ rat_idx, const int* __restrict__ time_idx,
    const __hip_bfloat16* __restrict__ wprep, float* __restrict__ out) {
  __shared__ __align__(16) unsigned char smem[SMEM_TOTAL];
  __hip_bfloat16* sW = (__hip_bfloat16*)(smem + W_OFF);
  __hip_bfloat16* sA = (__hip_bfloat16*)(smem + A_OFF);
  __hip_bfloat16* sB = (__hip_bfloat16*)(smem + B_OFF);
  __hip_bfloat16* sX = (__hip_bfloat16*)(smem + X_OFF);
  float* sUf    = (float*)(smem + SMALL);          // 128
  float* sAtt3  = (float*)(smem + SMALL + 512);    // 128
  int*   sIdx   = (int*)  (smem + SMALL + 1024);   // 192
  float* sUatt  = (float*)(smem + SMALL + 1792);   // 128
  float* sLogit = (float*)(smem + SMALL + 2304);   // 64
  float* sAtt   = (float*)(smem + SMALL + 2560);   // 64
  float* sPooled= (float*)(smem + SMALL + 2816);   // 128
  float* sComb  = (float*)(smem + SMALL + 3328);   // 128
  float* sH1    = (float*)(smem + SMALL + 3840);   // 32
  // aliases over dead regions (barrier-separated lifetimes)
  float* sUatt4 = (float*)(smem + X_OFF);          // 512 f, dead before x->sX
  float* sPool4 = (float*)(smem + W_OFF);          // 512 f, after last mfma
  float* sCombP = (float*)(smem + W_OFF + 2048);   // 512 f

  const int tid  = threadIdx.x;
  const int lane = tid & 63;
  const int wid  = tid >> 6;
  const int m16  = wid & 3;
  const int nh   = wid >> 2;
  const int b    = blockIdx.x;

  // ---- preload indices, user embedding, att3 ----
  if (tid < 192) {
    int c = tid >> 6, l = tid & 63;
    int v = 0;
    if (l < 50) {
      const int* p = (c == 0) ? item_idx : (c == 1) ? rat_idx : time_idx;
      v = p[b * 50 + l];
    }
    sIdx[tid] = v;
  } else if (tid < 320) {
    sAtt3[tid - 192] = att3_w[tid - 192];
  } else if (tid < 448) {
    sUf[tid - 320] = u2e[user_idx[b] * 128 + (tid - 320)];
  }
  __syncthreads();  // B0

  auto gather = [&](int c, const float* __restrict__ tab, __hip_bfloat16* dst) {
    const float4* t4 = (const float4*)tab;
#pragma unroll
    for (int i = 0; i < 2; ++i) {
      int g = tid + i * 512;
      if (g < 832) {                       // 52 rows x 16 chunks of 16B
        int row = g >> 4, kb = g & 15;
        float4 v0 = {0.f,0.f,0.f,0.f}, v1 = {0.f,0.f,0.f,0.f};
        if (row < 50) {
          long base = (long)sIdx[c * 64 + row] * 32 + kb * 2;
          v0 = t4[base]; v1 = t4[base + 1];
        }
        uint4 pk;
        pk.x = ((unsigned)bf_bits(v0.y) << 16) | bf_bits(v0.x);
        pk.y = ((unsigned)bf_bits(v0.w) << 16) | bf_bits(v0.z);
        pk.z = ((unsigned)bf_bits(v1.y) << 16) | bf_bits(v1.x);
        pk.w = ((unsigned)bf_bits(v1.w) << 16) | bf_bits(v1.z);
        *(uint4*)(dst + row * 128 + ((kb ^ (row & 15)) << 3)) = pk;
      }
    }
  };

  auto stage = [&](const __hip_bfloat16* __restrict__ src) {
#pragma unroll
    for (int i = 0; i < 4; ++i) {
      int g = tid + i * 512;                // 2048 x 16B = 32 KB
      __builtin_amdgcn_global_load_lds(
          (__attribute__((address_space(1))) void*)(void*)(src + g * 8),
          (__attribute__((address_space(3))) void*)(void*)(sW + g * 8), 16, 0, 0);
    }
  };

  f32x4 acc[4];
  const f32x4 zf = {0.f, 0.f, 0.f, 0.f};
  auto zacc = [&]() {
#pragma unroll
    for (int j = 0; j < 4; ++j) acc[j] = zf;
  };

  // ===== phase 0: gather item chunk, stage ne_w chunk0, u@att1_w[128:] partials =====
  gather(0, i2e, sA);
  stage(wprep + 0 * WCHUNK);
  {
    int q = tid >> 7, d = tid & 127;
    float s = 0.f;
    for (int k = q * 32; k < q * 32 + 32; ++k) s += sUf[k] * att1_w[(128 + k) * 128 + d];
    sUatt4[q * 128 + d] = s;
  }
  __syncthreads();  // B1

  // ===== ne layer (K=384): c0 =====
  zacc();
  mfma_chunk(sA, sW, acc, m16, nh, lane);
  gather(1, r2e, sB);
  if (tid < 128)
    sUatt[tid] = sUatt4[tid] + sUatt4[128 + tid] + sUatt4[256 + tid] + sUatt4[384 + tid];
  __syncthreads();  // B2
  stage(wprep + 1 * WCHUNK);
  gather(2, t2e, sA);   // sA free after c0
  __syncthreads();  // B3
  mfma_chunk(sB, sW, acc, m16, nh, lane);      // c1
  __syncthreads();  // B4
  stage(wprep + 2 * WCHUNK);
  __syncthreads();  // B5
  mfma_chunk(sA, sW, acc, m16, nh, lane);      // c2
  epilogue(acc, ne_b, nullptr, sB, m16, nh, lane);   // x1 -> sB
  __syncthreads();  // B6

  // ===== ne1 =====
  stage(wprep + 3 * WCHUNK);
  __syncthreads();  // B7
  zacc();
  mfma_chunk(sB, sW, acc, m16, nh, lane);
  epilogue(acc, ne1_b, nullptr, sX, m16, nh, lane);  // x -> sX (uatt4 alias dead)
  __syncthreads();  // B8

  // ===== att1: a1 = relu(x @ att1_w[:128] + uatt + b) =====
  stage(wprep + 4 * WCHUNK);
  __syncthreads();  // B9
  zacc();
  mfma_chunk(sX, sW, acc, m16, nh, lane);
  epilogue(acc, att1_b, sUatt, sA, m16, nh, lane);   // a1 -> sA
  __syncthreads();  // B10

  // ===== att2 =====
  stage(wprep + 5 * WCHUNK);
  __syncthreads();  // B11
  zacc();
  mfma_chunk(sA, sW, acc, m16, nh, lane);
  epilogue(acc, att2_b, nullptr, sB, m16, nh, lane); // a2 -> sB
  __syncthreads();  // B12

  // ===== logits: a2 @ att3 (8 lanes/row, swizzled reads) =====
  {
    int row = tid >> 3, p = tid & 7;
    const int base = row * 128;
    bf16x8 b0 = *(const bf16x8*)(sB + base + (((2 * p) ^ (row & 15)) << 3));
    bf16x8 b1 = *(const bf16x8*)(sB + base + (((2 * p + 1) ^ (row & 15)) << 3));
    float s = 0.f;
#pragma unroll
    for (int j = 0; j < 8; ++j) {
      s += (float)b0[j] * sAtt3[p * 16 + j];
      s += (float)b1[j] * sAtt3[p * 16 + 8 + j];
    }
    s += __shfl_xor(s, 1); s += __shfl_xor(s, 2); s += __shfl_xor(s, 4);
    if (p == 0) sLogit[row] = s + att3_b[0];
  }
  __syncthreads();  // B13

  // ===== softmax over 50 (wave 0) =====
  if (wid == 0) {
    float v = (lane < 50) ? sLogit[lane] : -3.4e38f;
    float m = v;
    for (int off = 32; off > 0; off >>= 1) m = fmaxf(m, __shfl_xor(m, off));
    float e = (lane < 50) ? __expf(v - m) : 0.f;
    float s = e;
    for (int off = 32; off > 0; off >>= 1) s += __shfl_xor(s, off);
    sAtt[lane] = e / s;
  }
  __syncthreads();  // B14

  // ===== pooled partials (4 per d), alias over sW =====
  {
    int q = tid >> 7, d = tid & 127;
    const int cblk = d >> 3, clo = d & 7;
    float s = 0.f;
    for (int l = q; l < 50; l += 4)
      s += sAtt[l] * (float)sX[l * 128 + ((cblk ^ (l & 15)) << 3) + clo];
    sPool4[q * 128 + d] = s;
  }
  __syncthreads();  // B15
  if (tid < 128)
    sPooled[tid] = sPool4[tid] + sPool4[128 + tid] + sPool4[256 + tid] + sPool4[384 + tid];
  __syncthreads();  // B16

  // ===== comb = relu(concat(u, pooled) @ lin_w + b), 4 k-partials =====
  {
    int q = tid >> 7, d = tid & 127;
    const float* inb = (q < 2) ? (sUf + q * 64) : (sPooled + (q - 2) * 64);
    const int base = q * 64;
    float s = 0.f;
    for (int j = 0; j < 64; ++j) s += inb[j] * lin_w[(base + j) * 128 + d];
    sCombP[q * 128 + d] = s;
  }
  __syncthreads();  // B17
  if (tid < 128)
    sComb[tid] = fmaxf(sCombP[tid] + sCombP[128 + tid] + sCombP[256 + tid] + sCombP[384 + tid]
                       + lin_b[tid], 0.f);
  __syncthreads();  // B18

  // ===== head entirely in wave 0 (same-wave LDS ordering, no barriers) =====
  if (wid == 0) {
    if (lane < 32) {
      float s = w1_b[lane];
      for (int k = 0; k < 128; ++k) s += sComb[k] * w1_w[k * 32 + lane];
      s = (s - bn1_m[lane]) * rsqrtf(bn1_v[lane] + 1e-5f) * bn1_g[lane] + bn1_b[lane];
      sH1[lane] = fmaxf(s, 0.f);
    }
    if (lane < 16) {
      float s = w2_b[lane];
      for (int k = 0; k < 32; ++k) s += sH1[k] * w2_w[k * 16 + lane];
      s = (s - bn2_m[lane]) * rsqrtf(bn2_v[lane] + 1e-5f) * bn2_g[lane] + bn2_b[lane];
      // h2 = relu(bn2(...)) — the fmaxf here was the R3 bug (missing ReLU)
      float p = fmaxf(s, 0.f) * w3_w[lane];
      p += __shfl_xor(p, 1); p += __shfl_xor(p, 2);
      p += __shfl_xor(p, 4); p += __shfl_xor(p, 8);
      if (lane == 0) out[b] = p + w3_b[0];
    }
  }
}

extern "C" void kernel_launch(void* const* d_in, const int* in_sizes, int n_in,
                              void* d_out, int out_size, void* d_ws, size_t ws_size,
                              hipStream_t stream) {
  const float* u2e    = (const float*)d_in[0];
  const float* i2e    = (const float*)d_in[1];
  const float* r2e    = (const float*)d_in[2];
  const float* t2e    = (const float*)d_in[3];
  const float* ne_w   = (const float*)d_in[4];
  const float* ne_b   = (const float*)d_in[5];
  const float* ne1_w  = (const float*)d_in[6];
  const float* ne1_b  = (const float*)d_in[7];
  const float* att1_w = (const float*)d_in[8];
  const float* att1_b = (const float*)d_in[9];
  const float* att2_w = (const float*)d_in[10];
  const float* att2_b = (const float*)d_in[11];
  const float* att3_w = (const float*)d_in[12];
  const float* att3_b = (const float*)d_in[13];
  const float* lin_w  = (const float*)d_in[14];
  const float* lin_b  = (const float*)d_in[15];
  const float* w1_w   = (const float*)d_in[16];
  const float* w1_b   = (const float*)d_in[17];
  const float* bn1_g  = (const float*)d_in[18];
  const float* bn1_b  = (const float*)d_in[19];
  const float* bn1_m  = (const float*)d_in[20];
  const float* bn1_v  = (const float*)d_in[21];
  const float* w2_w   = (const float*)d_in[22];
  const float* w2_b   = (const float*)d_in[23];
  const float* bn2_g  = (const float*)d_in[24];
  const float* bn2_b  = (const float*)d_in[25];
  const float* bn2_m  = (const float*)d_in[26];
  const float* bn2_v  = (const float*)d_in[27];
  const float* w3_w   = (const float*)d_in[28];
  const float* w3_b   = (const float*)d_in[29];
  const int* user_idx = (const int*)d_in[30];
  const int* item_idx = (const int*)d_in[31];
  const int* rat_idx  = (const int*)d_in[32];
  const int* time_idx = (const int*)d_in[33];
  __hip_bfloat16* wprep = (__hip_bfloat16*)d_ws;
  float* out = (float*)d_out;

  prep_weights_kernel<<<24, dim3(64, 4), 0, stream>>>(ne_w, ne1_w, att1_w, att2_w, wprep);
  graphdec_main<<<4096, 512, 0, stream>>>(
      u2e, i2e, r2e, t2e, ne_b, ne1_b, att1_w, att1_b, att3_w, att3_b, att2_b,
      lin_w, lin_b, w1_w, w1_b, bn1_g, bn1_b, bn1_m, bn1_v, w2_w, w2_b,
      bn2_g, bn2_b, bn2_m, bn2_v, w3_w, w3_b,
      user_idx, item_idx, rat_idx, time_idx, wprep, out);
}